// Round 1
// baseline (301.992 us; speedup 1.0000x reference)
//
#include <hip/hip_runtime.h>
#include <stdint.h>

// y[m][n] = sum_k x[m][k] * W[k][n] + b[n]
// M=262144, K=128, N=128. Memory-bound: 268 MB @ ~6 TB/s ~= 45 us.
// bf16 MFMA 16x16x32; W converted+swizzled to B-fragment order in LDS per block.

typedef __attribute__((ext_vector_type(8))) short bf16x8;   // 8 bf16 = 4 VGPRs
typedef __attribute__((ext_vector_type(4))) float f32x4;    // MFMA C/D

__device__ inline unsigned short f2bf(float f) {
  // round-to-nearest-even fp32 -> bf16 (inputs are finite normals)
  union { float f; uint32_t u; } v; v.f = f;
  uint32_t r = v.u + 0x7fffu + ((v.u >> 16) & 1u);
  return (unsigned short)(r >> 16);
}

__global__ __launch_bounds__(256, 4) void linear_kernel(
    const float* __restrict__ x, const float* __restrict__ w,
    const float* __restrict__ bias, float* __restrict__ y) {
  // W in B-fragment order: lds_w[((kk*8+nt)*64 + lane)*8 + j]
  //   = bf16( W[kk*32 + (lane>>4)*8 + j][nt*16 + (lane&15)] )
  __shared__ __align__(16) unsigned short lds_w[128 * 128];

  const int t = threadIdx.x;

  // ---- stage + convert + swizzle W into LDS (one-time; W is L2-hot) ----
  #pragma unroll
  for (int i = 0; i < 16; ++i) {
    int f4 = t + 256 * i;                      // float4 index, 0..4095 (coalesced)
    f32x4 wv = ((const f32x4*)w)[f4];
    #pragma unroll
    for (int c = 0; c < 4; ++c) {
      int flat = f4 * 4 + c;                   // flat = k*128 + n
      int k = flat >> 7, n = flat & 127;
      int kk = k >> 5, qk = (k >> 3) & 3, j = k & 7;
      int nt = n >> 4, lc = n & 15;
      lds_w[((kk * 8 + nt) * 64 + (qk * 16 + lc)) * 8 + j] = f2bf(wv[c]);
    }
  }

  const int lane = t & 63;
  const int wave = t >> 6;
  const int col  = lane & 15;                  // A-row / C-col within tile
  const int quad = lane >> 4;

  float breg[8];
  #pragma unroll
  for (int nt = 0; nt < 8; ++nt) breg[nt] = bias[nt * 16 + col];

  __syncthreads();

  const int block_row0 = blockIdx.x * 256;     // 256 rows per block

  for (int iter = 0; iter < 4; ++iter) {
    const int row0 = block_row0 + iter * 64 + wave * 16;

    // A fragments: lane holds x[row0 + (lane&15)][kk*32 + quad*8 + j], j=0..7
    const float* xp = x + (size_t)(row0 + col) * 128 + quad * 8;
    bf16x8 a[4];
    #pragma unroll
    for (int kk = 0; kk < 4; ++kk) {
      f32x4 f0 = *(const f32x4*)(xp + kk * 32);
      f32x4 f1 = *(const f32x4*)(xp + kk * 32 + 4);
      bf16x8 av;
      av[0] = f2bf(f0[0]); av[1] = f2bf(f0[1]); av[2] = f2bf(f0[2]); av[3] = f2bf(f0[3]);
      av[4] = f2bf(f1[0]); av[5] = f2bf(f1[1]); av[6] = f2bf(f1[2]); av[7] = f2bf(f1[3]);
      a[kk] = av;
    }

    float* yp = y + (size_t)row0 * 128 + col;
    #pragma unroll
    for (int nt = 0; nt < 8; ++nt) {
      // all 4 C regs of a lane share column nt*16+col -> init with bias
      f32x4 acc = {breg[nt], breg[nt], breg[nt], breg[nt]};
      #pragma unroll
      for (int kk = 0; kk < 4; ++kk) {
        bf16x8 b = *(const bf16x8*)&lds_w[((kk * 8 + nt) * 64 + lane) * 8];
        acc = __builtin_amdgcn_mfma_f32_16x16x32_bf16(a[kk], b, acc, 0, 0, 0);
      }
      // C/D: col = lane&15, row = quad*4 + r  [m89/m91]
      #pragma unroll
      for (int r = 0; r < 4; ++r)
        yp[(size_t)(quad * 4 + r) * 128 + nt * 16] = acc[r];
    }
  }
}

extern "C" void kernel_launch(void* const* d_in, const int* in_sizes, int n_in,
                              void* d_out, int out_size, void* d_ws, size_t ws_size,
                              hipStream_t stream) {
  const float* x    = (const float*)d_in[0];
  const float* w    = (const float*)d_in[1];
  const float* bias = (const float*)d_in[2];
  float* y = (float*)d_out;
  linear_kernel<<<1024, 256, 0, stream>>>(x, w, bias, y);
}

// Round 2
// 247.500 us; speedup vs baseline: 1.2202x; 1.2202x over previous
//
#include <hip/hip_runtime.h>
#include <stdint.h>

// y[m][n] = sum_k x[m][k] * W[k][n] + b[n]
// M=262144, K=128, N=128. Memory-bound: 268 MB @ ~6.3 TB/s ~= 43 us floor.
// bf16 MFMA 16x16x32, operands swapped (A=W^T, B=x) so each lane's 4 C-regs
// are 4 CONSECUTIVE y columns -> f32x4 nontemporal stores (no write-allocate RMW).

typedef __attribute__((ext_vector_type(8))) short bf16x8;   // 8 bf16 = 4 VGPRs
typedef __attribute__((ext_vector_type(4))) float f32x4;    // MFMA C/D

__device__ inline unsigned short f2bf(float f) {
  // round-to-nearest-even fp32 -> bf16 (inputs are finite normals)
  union { float f; uint32_t u; } v; v.f = f;
  uint32_t r = v.u + 0x7fffu + ((v.u >> 16) & 1u);
  return (unsigned short)(r >> 16);
}

__global__ __launch_bounds__(256, 4) void linear_kernel(
    const float* __restrict__ x, const float* __restrict__ w,
    const float* __restrict__ bias, float* __restrict__ y) {
  // W in A-fragment order (A = W^T tile):
  //   lds_w[((kk*8+nt)*64 + qk*16+lc)*8 + j] = bf16( W[kk*32+qk*8+j][nt*16+lc] )
  // i.e. A[m=lc][k=qk*8+j] = W[kk*32+k][nt*16+m]
  __shared__ __align__(16) unsigned short lds_w[128 * 128];

  const int t = threadIdx.x;

  // ---- stage W: column-wise scalar reads (L1/L2-hot, sector-coalesced),
  // ---- contiguous ds_write_b128 (conflict-free) ----
  #pragma unroll
  for (int gi = 0; gi < 8; ++gi) {
    int g = t + 256 * gi;            // group 0..2047; one group = 8 shorts = 16 B
    int fragid = g >> 6;             // kk*8+nt
    int slot   = g & 63;             // qk*16+lc
    int kk = fragid >> 3, nt = fragid & 7;
    int qk = slot >> 4,   lc = slot & 15;
    const float* wp = w + (size_t)(kk * 32 + qk * 8) * 128 + nt * 16 + lc;
    unsigned short tmp[8];
    #pragma unroll
    for (int j = 0; j < 8; ++j) tmp[j] = f2bf(wp[(size_t)j * 128]);
    *(bf16x8*)&lds_w[(size_t)g * 8] = *(const bf16x8*)tmp;
  }

  const int lane = t & 63;
  const int wave = t >> 6;
  const int col  = lane & 15;                  // y-row within 16-row tile
  const int quad = lane >> 4;

  // bias fragment: lane's 4 outputs are y cols nt*16 + quad*4 .. +3
  f32x4 bfrag[8];
  #pragma unroll
  for (int nt = 0; nt < 8; ++nt)
    bfrag[nt] = *(const f32x4*)(bias + nt * 16 + quad * 4);

  __syncthreads();

  const int block_row0 = blockIdx.x * 128;     // 128 rows per block

  #pragma unroll
  for (int iter = 0; iter < 2; ++iter) {
    const int row0 = block_row0 + iter * 64 + wave * 16;

    // B fragments (x): lane holds x[row0 + (lane&15)][kk*32 + quad*8 + j]
    const float* xp = x + (size_t)(row0 + col) * 128 + quad * 8;
    bf16x8 xf[4];
    #pragma unroll
    for (int kk = 0; kk < 4; ++kk) {
      f32x4 f0 = *(const f32x4*)(xp + kk * 32);
      f32x4 f1 = *(const f32x4*)(xp + kk * 32 + 4);
      bf16x8 av;
      av[0] = f2bf(f0[0]); av[1] = f2bf(f0[1]); av[2] = f2bf(f0[2]); av[3] = f2bf(f0[3]);
      av[4] = f2bf(f1[0]); av[5] = f2bf(f1[1]); av[6] = f2bf(f1[2]); av[7] = f2bf(f1[3]);
      xf[kk] = av;
    }

    float* yp = y + (size_t)(row0 + col) * 128;
    #pragma unroll
    for (int nt = 0; nt < 8; ++nt) {
      f32x4 acc = bfrag[nt];
      #pragma unroll
      for (int kk = 0; kk < 4; ++kk) {
        bf16x8 wf = *(const bf16x8*)&lds_w[((kk * 8 + nt) * 64 + lane) * 8];
        // D = (W tile)^T . (x tile)^T : D[m][n] = y[row0+n][nt*16+m]
        acc = __builtin_amdgcn_mfma_f32_16x16x32_bf16(wf, xf[kk], acc, 0, 0, 0);
      }
      // lane stores y[row0+col][nt*16 + quad*4 .. +3] as one f32x4, streaming
      __builtin_nontemporal_store(acc, (f32x4*)(yp + nt * 16 + quad * 4));
    }
  }
}

extern "C" void kernel_launch(void* const* d_in, const int* in_sizes, int n_in,
                              void* d_out, int out_size, void* d_ws, size_t ws_size,
                              hipStream_t stream) {
  const float* x    = (const float*)d_in[0];
  const float* w    = (const float*)d_in[1];
  const float* bias = (const float*)d_in[2];
  float* y = (float*)d_out;
  linear_kernel<<<2048, 256, 0, stream>>>(x, w, bias, y);
}